// Round 9
// baseline (300.112 us; speedup 1.0000x reference)
//
#include <hip/hip_runtime.h>

#define NB 8
#define NC 48
#define NHW 65536
#define NTOT (NB*NC*NHW)

typedef __attribute__((ext_vector_type(8))) short short8;
typedef __attribute__((ext_vector_type(4))) float f32x4;

__device__ __forceinline__ float lrelu(float v) { return v >= 0.0f ? v : 0.1f * v; }

__device__ __forceinline__ unsigned short f2bf(float f) {
    unsigned int u = __float_as_uint(f);
    return (unsigned short)((u + 0x7fffu + ((u >> 16) & 1u)) >> 16);
}
__device__ __forceinline__ float bf2f(unsigned short v) {
    return __uint_as_float((unsigned int)v << 16);
}

// ---------------------------------------------------------------------------
// Merged weight prep: transpose w1 (vector conv) + pack w21/w22 (MFMA A-frag).
// ---------------------------------------------------------------------------
__global__ __launch_bounds__(256) void prep_kernel(
    const float* __restrict__ w1, const float* __restrict__ w21,
    const float* __restrict__ w22, float* __restrict__ Wt1,
    unsigned short* __restrict__ Wp)
{
    int i = blockIdx.x * 256 + threadIdx.x;
    if (i < 2304) {
        int o = i / 48, c = i % 48;
        Wt1[c * 48 + o] = w1[i];
    } else if (i < 2304 + 6144) {
        int e0 = i - 2304;
        int m = e0 / 3072, e = e0 % 3072;
        int mt = e >> 10, r2 = e & 1023, ks = r2 >> 9, r3 = r2 & 511;
        int lane = r3 >> 3, j = r3 & 7;
        int o = mt * 16 + (lane & 15), c = ks * 32 + (lane >> 4) * 8 + j;
        const float* W = m ? w22 : w21;
        float v = (c < 48) ? W[o * 48 + c] : 0.f;
        Wp[e0] = f2bf(v);
    }
}

// ---------------------------------------------------------------------------
// Pack per-batch gn3-folded w3: Wp3[b] = bf16(w3 * sc3[b]), and
// b3f[b][o] = b3[o] + sum_c w3[o][c]*sh3[b][c].
// ---------------------------------------------------------------------------
__global__ __launch_bounds__(256) void pack_w3_kernel(
    const float* __restrict__ w3, const float* __restrict__ sc3,
    const float* __restrict__ sh3, const float* __restrict__ b3,
    unsigned short* __restrict__ Wp3, float* __restrict__ b3f)
{
    int i = blockIdx.x * 256 + threadIdx.x;
    if (i < 24576) {
        int b = i / 3072, e = i % 3072;
        int mt = e >> 10, r2 = e & 1023, ks = r2 >> 9, r3 = r2 & 511;
        int lane = r3 >> 3, j = r3 & 7;
        int o = mt * 16 + (lane & 15), c = ks * 32 + (lane >> 4) * 8 + j;
        float v = (c < 48) ? w3[o * 48 + c] * sc3[b * 48 + c] : 0.f;
        Wp3[i] = f2bf(v);
    } else if (i < 24960) {
        int k = i - 24576;
        int b = k / 48, o = k % 48;
        float s = b3[o];
        for (int c = 0; c < 48; c++) s = fmaf(w3[o * 48 + c], sh3[b * 48 + c], s);
        b3f[k] = s;
    }
}

// ---------------------------------------------------------------------------
// conv1 (fp32, exact for the LIF path): round-5 structure (best measured).
// Distance-1 double buffer, wave owns 12 outputs, lane owns 4 pixels.
// FMA order per output (c ascending) identical to all prior rounds.
// ---------------------------------------------------------------------------
__global__ __launch_bounds__(256) void conv48f_kernel(
    const float* __restrict__ in, const float* __restrict__ Wt,
    const float* __restrict__ bias, float* __restrict__ out,
    float* __restrict__ partial)
{
    int tid  = threadIdx.x;
    int lane = tid & 63;
    int wid  = tid >> 6;
    int blk  = blockIdx.x;
    int b    = blk >> 8;
    int px0  = (blk & 255) * 256 + lane * 4;
    int ob   = __builtin_amdgcn_readfirstlane(wid * 12);

    size_t base = (size_t)b * NC * NHW + px0;

    float acc[12][4];
#pragma unroll
    for (int o = 0; o < 12; o++) {
        float bz = bias[ob + o];
#pragma unroll
        for (int j = 0; j < 4; j++) acc[o][j] = bz;
    }

    float xv[2][4][4];
#pragma unroll
    for (int cc = 0; cc < 4; cc++) {
        float4 t = *(const float4*)(in + base + (size_t)cc * NHW);
        xv[0][cc][0] = t.x; xv[0][cc][1] = t.y;
        xv[0][cc][2] = t.z; xv[0][cc][3] = t.w;
    }

#pragma unroll
    for (int k = 0; k < 12; k++) {
        const int cur = k & 1;
        if (k < 11) {
            int cn = (k + 1) * 4;
#pragma unroll
            for (int cc = 0; cc < 4; cc++) {
                float4 t = *(const float4*)(in + base + (size_t)(cn + cc) * NHW);
                xv[cur ^ 1][cc][0] = t.x; xv[cur ^ 1][cc][1] = t.y;
                xv[cur ^ 1][cc][2] = t.z; xv[cur ^ 1][cc][3] = t.w;
            }
        }
        int c0 = k * 4;
#pragma unroll
        for (int cc = 0; cc < 4; cc++) {
            const float* wrow = Wt + (c0 + cc) * 48 + ob;
#pragma unroll
            for (int o = 0; o < 12; o++) {
                float wv = wrow[o];
#pragma unroll
                for (int j = 0; j < 4; j++)
                    acc[o][j] = fmaf(xv[cur][cc][j], wv, acc[o][j]);
            }
        }
        __builtin_amdgcn_sched_barrier(0);
    }

#pragma unroll
    for (int o = 0; o < 12; o++) {
        float4 t = {acc[o][0], acc[o][1], acc[o][2], acc[o][3]};
        *(float4*)(out + base + (size_t)(ob + o) * NHW) = t;
    }

#pragma unroll
    for (int i = 0; i < 6; i++) {
        float s = 0.f, q = 0.f;
#pragma unroll
        for (int k = 0; k < 2; k++)
#pragma unroll
            for (int j = 0; j < 4; j++) {
                float a = acc[2 * i + k][j];
                s += a;
                q = fmaf(a, a, q);
            }
#pragma unroll
        for (int off = 32; off; off >>= 1) {
            s += __shfl_down(s, off);
            q += __shfl_down(q, off);
        }
        if (lane == 0) {
            partial[(size_t)blk * 48 + ob + 2 * i]     = s;
            partial[(size_t)blk * 48 + ob + 2 * i + 1] = q;
        }
    }
}

// ---------------------------------------------------------------------------
// Depthwise 3x3 STATS-ONLY pass: computes t2 values (gn1+leaky fused on input
// reads) and emits per-block (s,ss) partials for gn2 — t2 is NOT stored.
// Arithmetic identical to the former dwconv_kernel (bit-stable).
// ---------------------------------------------------------------------------
__global__ __launch_bounds__(256) void dwconv_stats_kernel(
    const float* __restrict__ in, const float* __restrict__ wdw,
    const float* __restrict__ bdw,
    const float* __restrict__ scale, const float* __restrict__ shift,
    float* __restrict__ partial)
{
    int tid = threadIdx.x;
    int blk = blockIdx.x;
    int bc  = blk >> 6;
    int rg  = blk & 63;
    int r   = tid >> 6;
    int w4  = tid & 63;
    int h   = rg * 4 + r;
    int c0  = w4 * 4;
    int c   = bc % 48;

    const float* plane = in + (size_t)bc * NHW;
    float sc = scale[bc], sh = shift[bc];

    float wk[9];
#pragma unroll
    for (int i = 0; i < 9; i++) wk[i] = wdw[c * 9 + i];
    float bv = bdw[c];

    float raw[3][6];
#pragma unroll
    for (int dy = 0; dy < 3; dy++) {
        int hh  = h + dy - 1;
        int hcl = min(max(hh, 0), 255);
        const float* row = plane + hcl * 256;
        float4 m  = *(const float4*)(row + c0);
        float lft = row[(w4 > 0) ? (c0 - 1) : 0];
        float rgt = row[(w4 < 63) ? (c0 + 4) : 255];
        raw[dy][0] = lft; raw[dy][1] = m.x; raw[dy][2] = m.y;
        raw[dy][3] = m.z; raw[dy][4] = m.w; raw[dy][5] = rgt;
    }

    float v[3][6];
#pragma unroll
    for (int dy = 0; dy < 3; dy++) {
        int hh = h + dy - 1;
        bool hv = (hh >= 0) && (hh < 256);
#pragma unroll
        for (int j = 0; j < 6; j++) {
            bool valid = hv && !(j == 0 && w4 == 0) && !(j == 5 && w4 == 63);
            float t = lrelu(fmaf(raw[dy][j], sc, sh));
            v[dy][j] = valid ? t : 0.f;
        }
    }

    float acc[4] = {bv, bv, bv, bv};
#pragma unroll
    for (int dy = 0; dy < 3; dy++)
#pragma unroll
        for (int dx = 0; dx < 3; dx++) {
            float wv = wk[dy * 3 + dx];
#pragma unroll
            for (int j = 0; j < 4; j++)
                acc[j] = fmaf(v[dy][j + dx], wv, acc[j]);
        }

    float s = (acc[0] + acc[1]) + (acc[2] + acc[3]);
    float q = fmaf(acc[0], acc[0], fmaf(acc[1], acc[1],
              fmaf(acc[2], acc[2], acc[3] * acc[3])));
#pragma unroll
    for (int off = 32; off; off >>= 1) {
        s += __shfl_down(s, off);
        q += __shfl_down(q, off);
    }
    __shared__ float red[8];
    int lane = tid & 63, wid = tid >> 6;
    if (lane == 0) { red[wid * 2] = s; red[wid * 2 + 1] = q; }
    __syncthreads();
    if (tid == 0) {
        partial[(size_t)blk * 2]     = red[0] + red[2] + red[4] + red[6];
        partial[(size_t)blk * 2 + 1] = red[1] + red[3] + red[5] + red[7];
    }
}

// ---------------------------------------------------------------------------
// Fused dwconv-recompute + gn2 + leaky + LIF over BOTH axes. Reads t1 (with
// halo) and recomputes t2 bit-identically to dwconv_stats (same FMA order),
// then runs both LIF recurrences. Spikes packed: bit0 = H-axis, bit1 = W-axis.
// ---------------------------------------------------------------------------
__global__ __launch_bounds__(256) void lif_dw_kernel(
    const float* __restrict__ in, const float* __restrict__ wdw,
    const float* __restrict__ bdw,
    const float* __restrict__ sc1v, const float* __restrict__ sh1v,
    const float* __restrict__ sc2v, const float* __restrict__ sh2v,
    const float* __restrict__ tau1p, const float* __restrict__ vth1p,
    const float* __restrict__ tau2p, const float* __restrict__ vth2p,
    unsigned char* __restrict__ spk)
{
    int id  = blockIdx.x * 256 + threadIdx.x;
    int ww4 = id & 15;
    int hh  = (id >> 4) & 63;
    int bc  = id >> 10;
    int c   = bc % 48;

    const float* plane = in + (size_t)bc * NHW;
    float s1 = sc1v[bc], h1 = sh1v[bc];
    float s2 = sc2v[bc], h2 = sh2v[bc];
    float tau1 = tau1p[0], vth1 = vth1p[0];
    float tau2 = tau2p[0], vth2 = vth2p[0];

    float wk[9];
#pragma unroll
    for (int i = 0; i < 9; i++) wk[i] = wdw[c * 9 + i];
    float bv = bdw[c];

    float v[4][4][4];   // gn2+leaky(dwconv) values, [t][u][j]
#pragma unroll
    for (int t = 0; t < 4; t++) {
        int h = hh + 64 * t;
#pragma unroll
        for (int u = 0; u < 4; u++) {
            int c0 = 64 * u + ww4 * 4;
            // identical load/validity/FMA structure to dwconv_stats
            float raw[3][6];
#pragma unroll
            for (int dy = 0; dy < 3; dy++) {
                int hp  = h + dy - 1;
                int hcl = min(max(hp, 0), 255);
                const float* row = plane + hcl * 256;
                float4 m  = *(const float4*)(row + c0);
                float lft = row[(c0 > 0) ? (c0 - 1) : 0];
                float rgt = row[(c0 < 252) ? (c0 + 4) : 255];
                raw[dy][0] = lft; raw[dy][1] = m.x; raw[dy][2] = m.y;
                raw[dy][3] = m.z; raw[dy][4] = m.w; raw[dy][5] = rgt;
            }
            float vv[3][6];
#pragma unroll
            for (int dy = 0; dy < 3; dy++) {
                int hp = h + dy - 1;
                bool hv = (hp >= 0) && (hp < 256);
#pragma unroll
                for (int j = 0; j < 6; j++) {
                    bool valid = hv && !(j == 0 && c0 == 0) && !(j == 5 && c0 == 252);
                    float t0 = lrelu(fmaf(raw[dy][j], s1, h1));
                    vv[dy][j] = valid ? t0 : 0.f;
                }
            }
            float a[4] = {bv, bv, bv, bv};
#pragma unroll
            for (int dy = 0; dy < 3; dy++)
#pragma unroll
                for (int dx = 0; dx < 3; dx++) {
                    float wv = wk[dy * 3 + dx];
#pragma unroll
                    for (int j = 0; j < 4; j++)
                        a[j] = fmaf(vv[dy][j + dx], wv, a[j]);
                }
            // gn2 + leaky
#pragma unroll
            for (int j = 0; j < 4; j++)
                v[t][u][j] = lrelu(fmaf(a[j], s2, h2));
        }
    }

    unsigned int oC[4][4];
#pragma unroll
    for (int t = 0; t < 4; t++)
#pragma unroll
        for (int u = 0; u < 4; u++) oC[t][u] = 0u;

    // LIF over height chunks -> bit 0
    {
        float mem[16];
#pragma unroll
        for (int k = 0; k < 16; k++) mem[k] = 0.f;
#pragma unroll
        for (int t = 0; t < 4; t++)
#pragma unroll
            for (int u = 0; u < 4; u++)
#pragma unroll
                for (int j = 0; j < 4; j++) {
                    float m = fmaf(mem[u * 4 + j], tau1, v[t][u][j]);
                    bool s = m > vth1;
                    oC[t][u] |= (s ? 1u : 0u) << (8 * j);
                    mem[u * 4 + j] = s ? 0.f : m;
                }
    }
    // LIF over width chunks -> bit 1
    {
        float mem[16];
#pragma unroll
        for (int k = 0; k < 16; k++) mem[k] = 0.f;
#pragma unroll
        for (int u = 0; u < 4; u++)
#pragma unroll
            for (int t = 0; t < 4; t++)
#pragma unroll
                for (int j = 0; j < 4; j++) {
                    float m = fmaf(mem[t * 4 + j], tau2, v[t][u][j]);
                    bool s = m > vth2;
                    oC[t][u] |= (s ? 2u : 0u) << (8 * j);
                    mem[t * 4 + j] = s ? 0.f : m;
                }
    }

#pragma unroll
    for (int t = 0; t < 4; t++)
#pragma unroll
        for (int u = 0; u < 4; u++) {
            size_t off = (size_t)bc * NHW + (hh + 64 * t) * 256 + 64 * u + ww4 * 4;
            *(unsigned int*)(spk + off) = oC[t][u];
        }
}

// ---------------------------------------------------------------------------
// MFMA 1x1 conv on packed spikes -> bf16 NHWC + per-block channel stats.
// Both convs in one launch: blk>>11 selects bit (0=H,1=W), weights, outputs.
// ---------------------------------------------------------------------------
__global__ __launch_bounds__(256) void conv_mfma_u8_kernel(
    const unsigned char* __restrict__ spk,
    const unsigned short* __restrict__ Wp,
    const float* __restrict__ bias0, const float* __restrict__ bias1,
    unsigned short* __restrict__ out0, unsigned short* __restrict__ out1,
    float* __restrict__ P0, float* __restrict__ P1)
{
    __shared__ unsigned short Xs[64 * 260];
    __shared__ float red[4][96];

    int tid = threadIdx.x, lane = tid & 63, wid = tid >> 6;
    int l15 = lane & 15, g = lane >> 4;
    int blk2 = blockIdx.x;
    int m    = blk2 >> 11;
    int blk  = blk2 & 2047;
    int b = blk >> 8, pix0 = (blk & 255) * 256;

    const float*          bias = m ? bias1 : bias0;
    unsigned short*       outp = m ? out1 : out0;
    float*                P    = m ? P1 : P0;
    const unsigned short* Wm   = Wp + m * 3072;
    unsigned char         msk  = (unsigned char)(1u << m);

    // stage 48x256 packed-u8 -> bf16, channel-major rows (stride 260 ushorts)
    {
        int px = (tid & 63) * 4;
        int cw = tid >> 6;
#pragma unroll
        for (int r = 0; r < 12; r++) {
            int c = r * 4 + cw;
            uchar4 v = *(const uchar4*)(spk + ((size_t)(b * 48 + c) << 16) + pix0 + px);
            ushort4 u;
            u.x = (v.x & msk) ? 0x3F80 : 0; u.y = (v.y & msk) ? 0x3F80 : 0;
            u.z = (v.z & msk) ? 0x3F80 : 0; u.w = (v.w & msk) ? 0x3F80 : 0;
            *(ushort4*)&Xs[c * 260 + px] = u;
        }
        unsigned int* Xw = (unsigned int*)Xs;
        for (int i = tid; i < 2080; i += 256) Xw[6240 + i] = 0u;
    }
    __syncthreads();

    short8 af[3][2];
#pragma unroll
    for (int mt = 0; mt < 3; mt++)
#pragma unroll
        for (int ks = 0; ks < 2; ks++)
            af[mt][ks] = *(const short8*)(Wm + (mt * 2 + ks) * 512 + lane * 8);

    f32x4 acc[3][4];
#pragma unroll
    for (int mt = 0; mt < 3; mt++) {
        f32x4 bv = *(const f32x4*)(bias + mt * 16 + g * 4);
#pragma unroll
        for (int nt = 0; nt < 4; nt++) acc[mt][nt] = bv;
    }

#pragma unroll
    for (int nt = 0; nt < 4; nt++) {
        int pixl = wid * 64 + nt * 16 + l15;
#pragma unroll
        for (int ks = 0; ks < 2; ks++) {
            int rb = ks * 32 + g * 8;
            short8 bf;
#pragma unroll
            for (int j = 0; j < 8; j++) bf[j] = (short)Xs[(rb + j) * 260 + pixl];
#pragma unroll
            for (int mt = 0; mt < 3; mt++)
                acc[mt][nt] = __builtin_amdgcn_mfma_f32_16x16x32_bf16(
                    af[mt][ks], bf, acc[mt][nt], 0, 0, 0);
        }
    }

    // store NHWC bf16
#pragma unroll
    for (int nt = 0; nt < 4; nt++) {
        int px = pix0 + wid * 64 + nt * 16 + l15;
        size_t obase = ((size_t)b * NHW + px) * 48;
#pragma unroll
        for (int mt = 0; mt < 3; mt++) {
            ushort4 o;
            o.x = f2bf(acc[mt][nt][0]); o.y = f2bf(acc[mt][nt][1]);
            o.z = f2bf(acc[mt][nt][2]); o.w = f2bf(acc[mt][nt][3]);
            *(ushort4*)(outp + obase + mt * 16 + g * 4) = o;
        }
    }

    // per-channel (s, q) stats
#pragma unroll
    for (int mt = 0; mt < 3; mt++) {
#pragma unroll
        for (int r = 0; r < 4; r++) {
            float sl = 0.f, sq = 0.f;
#pragma unroll
            for (int nt = 0; nt < 4; nt++) {
                float a = acc[mt][nt][r];
                sl += a;
                sq = fmaf(a, a, sq);
            }
#pragma unroll
            for (int off = 1; off < 16; off <<= 1) {
                sl += __shfl_xor(sl, off);
                sq += __shfl_xor(sq, off);
            }
            if (l15 == 0) {
                int ch = mt * 16 + g * 4 + r;
                red[wid][ch * 2]     = sl;
                red[wid][ch * 2 + 1] = sq;
            }
        }
    }
    __syncthreads();
    if (tid < 96)
        P[(size_t)blk * 96 + tid] = red[0][tid] + red[1][tid] + red[2][tid] + red[3][tid];
}

// ---------------------------------------------------------------------------
// MFMA 1x1 conv: bf16 NHWC s_pre -> fp32 NCHW out. gn3 folded into per-batch
// weights. All 8 B-fragments prefetched before the MFMA chain.
// ---------------------------------------------------------------------------
__global__ __launch_bounds__(256) void conv_mfma_f32out_kernel(
    const unsigned short* __restrict__ sp, const unsigned short* __restrict__ Wp3,
    const float* __restrict__ b3f, float* __restrict__ outp)
{
    int tid = threadIdx.x, lane = tid & 63, wid = tid >> 6;
    int l15 = lane & 15, g = lane >> 4;
    int blk = blockIdx.x, b = blk >> 8, pix0 = (blk & 255) * 256;

    const unsigned short* Wb = Wp3 + b * 3072;

    short8 bfr[4][2];
#pragma unroll
    for (int nt = 0; nt < 4; nt++) {
        size_t pb = ((size_t)b * NHW + pix0 + wid * 64 + nt * 16 + l15) * 48;
#pragma unroll
        for (int ks = 0; ks < 2; ks++)
            bfr[nt][ks] = *(const short8*)(sp + pb + ks * 32 + g * 8);
    }

    short8 af[3][2];
#pragma unroll
    for (int mt = 0; mt < 3; mt++)
#pragma unroll
        for (int ks = 0; ks < 2; ks++)
            af[mt][ks] = *(const short8*)(Wb + (mt * 2 + ks) * 512 + lane * 8);

    f32x4 acc[3][4];
#pragma unroll
    for (int mt = 0; mt < 3; mt++) {
        f32x4 bv = *(const f32x4*)(b3f + b * 48 + mt * 16 + g * 4);
#pragma unroll
        for (int nt = 0; nt < 4; nt++) acc[mt][nt] = bv;
    }

#pragma unroll
    for (int nt = 0; nt < 4; nt++)
#pragma unroll
        for (int ks = 0; ks < 2; ks++)
#pragma unroll
            for (int mt = 0; mt < 3; mt++)
                acc[mt][nt] = __builtin_amdgcn_mfma_f32_16x16x32_bf16(
                    af[mt][ks], bfr[nt][ks], acc[mt][nt], 0, 0, 0);

#pragma unroll
    for (int nt = 0; nt < 4; nt++) {
        int px = pix0 + wid * 64 + nt * 16 + l15;
#pragma unroll
        for (int mt = 0; mt < 3; mt++)
#pragma unroll
            for (int r = 0; r < 4; r++)
                outp[((size_t)(b * 48 + mt * 16 + g * 4 + r) << 16) + px] = acc[mt][nt][r];
    }
}

// ---------------------------------------------------------------------------
// s_pre = leaky(gn4(t3)) + leaky(gn5(t4)) on NHWC bf16, + gn3 stats.
// ---------------------------------------------------------------------------
__global__ __launch_bounds__(256) void add_gn_nhwc_kernel(
    const unsigned short* __restrict__ a, const unsigned short* __restrict__ bb,
    const float* __restrict__ sc4, const float* __restrict__ sh4,
    const float* __restrict__ sc5, const float* __restrict__ sh5,
    unsigned short* __restrict__ o, float* __restrict__ P)
{
    __shared__ float red[4][96];
    int tid = threadIdx.x, lane = tid & 63, wid = tid >> 6;
    int g = lane >> 2, s = lane & 3, cs = s * 12;
    int blk = blockIdx.x;
    int pg = blk * 64 + wid * 16 + g;
    int b = pg >> 16;

    float sa[12], ha[12], sb[12], hb[12];
    {
        const f32x4* q;
        q = (const f32x4*)(sc4 + b * 48 + cs);
        f32x4 t0 = q[0], t1 = q[1], t2 = q[2];
#pragma unroll
        for (int i = 0; i < 4; i++) { sa[i] = t0[i]; sa[4 + i] = t1[i]; sa[8 + i] = t2[i]; }
        q = (const f32x4*)(sh4 + b * 48 + cs);
        t0 = q[0]; t1 = q[1]; t2 = q[2];
#pragma unroll
        for (int i = 0; i < 4; i++) { ha[i] = t0[i]; ha[4 + i] = t1[i]; ha[8 + i] = t2[i]; }
        q = (const f32x4*)(sc5 + b * 48 + cs);
        t0 = q[0]; t1 = q[1]; t2 = q[2];
#pragma unroll
        for (int i = 0; i < 4; i++) { sb[i] = t0[i]; sb[4 + i] = t1[i]; sb[8 + i] = t2[i]; }
        q = (const f32x4*)(sh5 + b * 48 + cs);
        t0 = q[0]; t1 = q[1]; t2 = q[2];
#pragma unroll
        for (int i = 0; i < 4; i++) { hb[i] = t0[i]; hb[4 + i] = t1[i]; hb[8 + i] = t2[i]; }
    }

    size_t base = (size_t)pg * 48 + cs;
    ushort4 A0 = *(const ushort4*)(a + base);
    ushort4 A1 = *(const ushort4*)(a + base + 4);
    ushort4 A2 = *(const ushort4*)(a + base + 8);
    ushort4 B0 = *(const ushort4*)(bb + base);
    ushort4 B1 = *(const ushort4*)(bb + base + 4);
    ushort4 B2 = *(const ushort4*)(bb + base + 8);

    unsigned short av[12] = {A0.x, A0.y, A0.z, A0.w, A1.x, A1.y, A1.z, A1.w,
                             A2.x, A2.y, A2.z, A2.w};
    unsigned short bv[12] = {B0.x, B0.y, B0.z, B0.w, B1.x, B1.y, B1.z, B1.w,
                             B2.x, B2.y, B2.z, B2.w};

    float tv[12];
    unsigned short ov[12];
#pragma unroll
    for (int i = 0; i < 12; i++) {
        float fa = bf2f(av[i]);
        float fb = bf2f(bv[i]);
        float t = lrelu(fmaf(fa, sa[i], ha[i])) + lrelu(fmaf(fb, sb[i], hb[i]));
        tv[i] = t;
        ov[i] = f2bf(t);
    }
    ushort4 O0 = {ov[0], ov[1], ov[2], ov[3]};
    ushort4 O1 = {ov[4], ov[5], ov[6], ov[7]};
    ushort4 O2 = {ov[8], ov[9], ov[10], ov[11]};
    *(ushort4*)(o + base)     = O0;
    *(ushort4*)(o + base + 4) = O1;
    *(ushort4*)(o + base + 8) = O2;

#pragma unroll
    for (int i = 0; i < 12; i++) {
        float ss = tv[i], qq = tv[i] * tv[i];
#pragma unroll
        for (int off = 32; off >= 4; off >>= 1) {
            ss += __shfl_down(ss, off);
            qq += __shfl_down(qq, off);
        }
        if (lane < 4) {
            red[wid][(cs + i) * 2]     = ss;
            red[wid][(cs + i) * 2 + 1] = qq;
        }
    }
    __syncthreads();
    if (tid < 96)
        P[(size_t)blk * 96 + tid] = red[0][tid] + red[1][tid] + red[2][tid] + red[3][tid];
}

// ---------------------------------------------------------------------------
// Reduce P1 layout (conv1): P[(b*256+chunk)*48 + 2g {,+1}]
// ---------------------------------------------------------------------------
__global__ __launch_bounds__(256) void reduce_chunked48_kernel(
    const float* __restrict__ P, const float* __restrict__ gamma,
    const float* __restrict__ beta,
    float* __restrict__ scale, float* __restrict__ shift)
{
    int b = blockIdx.x / 24, g = blockIdx.x % 24;
    int tid = threadIdx.x;
    double s = (double)P[(size_t)(b * 256 + tid) * 48 + 2 * g];
    double q = (double)P[(size_t)(b * 256 + tid) * 48 + 2 * g + 1];
    __shared__ double ls[256], lq[256];
    ls[tid] = s; lq[tid] = q;
    __syncthreads();
    for (int st = 128; st; st >>= 1) {
        if (tid < st) { ls[tid] += ls[tid + st]; lq[tid] += lq[tid + st]; }
        __syncthreads();
    }
    if (tid == 0) {
        double mu  = ls[0] / 131072.0;
        double var = lq[0] / 131072.0 - mu * mu;
        double rstd = 1.0 / sqrt(var + 1e-5);
#pragma unroll
        for (int j = 0; j < 2; j++) {
            int c = 2 * g + j;
            double scv = rstd * (double)gamma[c];
            scale[b * 48 + c] = (float)scv;
            shift[b * 48 + c] = (float)((double)beta[c] - mu * scv);
        }
    }
}

// ---------------------------------------------------------------------------
// Reduce per-plane partials (dwconv): P[((b*48+c)*chunks + k)*2 {,+1}]
// ---------------------------------------------------------------------------
__global__ __launch_bounds__(256) void reduce_plane_kernel(
    const float* __restrict__ P, int chunks,
    const float* __restrict__ gamma, const float* __restrict__ beta,
    float* __restrict__ scale, float* __restrict__ shift)
{
    int b = blockIdx.x / 24, g = blockIdx.x % 24;
    int tid = threadIdx.x;
    double s = 0.0, q = 0.0;
    for (int i = tid; i < 2 * chunks; i += 256) {
        int j = (i >= chunks) ? 1 : 0;
        int k = i - j * chunks;
        const float* p = P + ((size_t)((b * 48 + 2 * g + j) * chunks + k)) * 2;
        s += (double)p[0];
        q += (double)p[1];
    }
    __shared__ double ls[256], lq[256];
    ls[tid] = s; lq[tid] = q;
    __syncthreads();
    for (int st = 128; st; st >>= 1) {
        if (tid < st) { ls[tid] += ls[tid + st]; lq[tid] += lq[tid + st]; }
        __syncthreads();
    }
    if (tid == 0) {
        double mu  = ls[0] / 131072.0;
        double var = lq[0] / 131072.0 - mu * mu;
        double rstd = 1.0 / sqrt(var + 1e-5);
#pragma unroll
        for (int j = 0; j < 2; j++) {
            int c = 2 * g + j;
            double scv = rstd * (double)gamma[c];
            scale[b * 48 + c] = (float)scv;
            shift[b * 48 + c] = (float)((double)beta[c] - mu * scv);
        }
    }
}

// ---------------------------------------------------------------------------
// Reduce row-partials P[row*96 + c*2 {,+1}]; one or two sets per launch.
// ---------------------------------------------------------------------------
__global__ __launch_bounds__(256) void reduce_rows48_dual_kernel(
    const float* __restrict__ PA, const float* __restrict__ PB, int rows_per_b,
    const float* __restrict__ gA, const float* __restrict__ beA,
    const float* __restrict__ gB, const float* __restrict__ beB,
    float* __restrict__ scA, float* __restrict__ shA,
    float* __restrict__ scB, float* __restrict__ shB)
{
    int sel = blockIdx.x / 192;
    int idx = blockIdx.x % 192;
    const float* P     = sel ? PB : PA;
    const float* gamma = sel ? gB : gA;
    const float* beta  = sel ? beB : beA;
    float* scale = sel ? scB : scA;
    float* shift = sel ? shB : shA;

    int b = idx / 24, g = idx % 24;
    int tid = threadIdx.x;
    double s = 0.0, q = 0.0;
    for (int r = tid; r < rows_per_b; r += 256) {
        const float* p = P + (size_t)(b * rows_per_b + r) * 96;
        s += (double)p[4 * g] + (double)p[4 * g + 2];
        q += (double)p[4 * g + 1] + (double)p[4 * g + 3];
    }
    __shared__ double ls[256], lq[256];
    ls[tid] = s; lq[tid] = q;
    __syncthreads();
    for (int st = 128; st; st >>= 1) {
        if (tid < st) { ls[tid] += ls[tid + st]; lq[tid] += lq[tid + st]; }
        __syncthreads();
    }
    if (tid == 0) {
        double mu  = ls[0] / 131072.0;
        double var = lq[0] / 131072.0 - mu * mu;
        double rstd = 1.0 / sqrt(var + 1e-5);
#pragma unroll
        for (int j = 0; j < 2; j++) {
            int c = 2 * g + j;
            double scv = rstd * (double)gamma[c];
            scale[b * 48 + c] = (float)scv;
            shift[b * 48 + c] = (float)((double)beta[c] - mu * scv);
        }
    }
}

// ---------------------------------------------------------------------------
extern "C" void kernel_launch(void* const* d_in, const int* in_sizes, int n_in,
                              void* d_out, int out_size, void* d_ws, size_t ws_size,
                              hipStream_t stream)
{
    const float* x    = (const float*)d_in[0];
    const float* w1   = (const float*)d_in[1];
    const float* b1   = (const float*)d_in[2];
    const float* wdw  = (const float*)d_in[3];
    const float* bdw  = (const float*)d_in[4];
    const float* w21  = (const float*)d_in[5];
    const float* b21  = (const float*)d_in[6];
    const float* w22  = (const float*)d_in[7];
    const float* b22  = (const float*)d_in[8];
    const float* w3   = (const float*)d_in[9];
    const float* b3   = (const float*)d_in[10];
    const float* g1   = (const float*)d_in[11];
    const float* be1  = (const float*)d_in[12];
    const float* g2   = (const float*)d_in[13];
    const float* be2  = (const float*)d_in[14];
    const float* g3   = (const float*)d_in[15];
    const float* be3  = (const float*)d_in[16];
    const float* g4   = (const float*)d_in[17];
    const float* be4  = (const float*)d_in[18];
    const float* g5   = (const float*)d_in[19];
    const float* be5  = (const float*)d_in[20];
    const float* tau1 = (const float*)d_in[21];
    const float* vth1 = (const float*)d_in[22];
    const float* tau2 = (const float*)d_in[23];
    const float* vth2 = (const float*)d_in[24];

    float* out = (float*)d_out;
    char*  ws  = (char*)d_ws;

    // ws layout
    float*          A   = (float*)ws;                                // t1 fp32 (NTOT)
    unsigned short* Tb3 = (unsigned short*)ws;                       // t3/s_pre bf16 NHWC
    unsigned short* Tb4 = Tb3 + (size_t)NTOT;                        // t4 bf16 NHWC
    unsigned char*  S   = (unsigned char*)(ws + (size_t)NTOT * 4);   // packed spikes (bit0=H,bit1=W)
    char* p = ws + (size_t)NTOT * 5;
    float* P1 = (float*)p;  p += (size_t)2048 * 48 * 4;
    float* P2 = (float*)p;  p += (size_t)24576 * 2 * 4;
    float* P4 = (float*)p;  p += (size_t)2048 * 96 * 4;
    float* P5 = (float*)p;  p += (size_t)2048 * 96 * 4;
    float* P6 = (float*)p;  p += (size_t)8192 * 96 * 4;
    float* sc1 = (float*)p; p += 384 * 4;  float* sh1 = (float*)p; p += 384 * 4;
    float* sc2 = (float*)p; p += 384 * 4;  float* sh2 = (float*)p; p += 384 * 4;
    float* sc3 = (float*)p; p += 384 * 4;  float* sh3 = (float*)p; p += 384 * 4;
    float* sc4 = (float*)p; p += 384 * 4;  float* sh4 = (float*)p; p += 384 * 4;
    float* sc5 = (float*)p; p += 384 * 4;  float* sh5 = (float*)p; p += 384 * 4;
    float*          Wt1  = (float*)p;          p += 2304 * 4;
    unsigned short* Wp2x = (unsigned short*)p; p += 6144 * 2;
    unsigned short* Wp3  = (unsigned short*)p; p += 24576 * 2;
    float*          b3f  = (float*)p;          p += 384 * 4;

    // 0) weight prep (merged)
    prep_kernel<<<33, 256, 0, stream>>>(w1, w21, w22, Wt1, Wp2x);

    // 1) t1 = conv1x1(x, w1) + b1 -> A (fp32 NCHW); gn1 partials
    conv48f_kernel<<<2048, 256, 0, stream>>>(x, Wt1, b1, A, P1);
    reduce_chunked48_kernel<<<192, 256, 0, stream>>>(P1, g1, be1, sc1, sh1);

    // 2) gn2 partials from dwconv values (t2 never stored)
    dwconv_stats_kernel<<<24576, 256, 0, stream>>>(A, wdw, bdw, sc1, sh1, P2);
    reduce_plane_kernel<<<192, 256, 0, stream>>>(P2, 64, g2, be2, sc2, sh2);

    // 3) fused dwconv-recompute + gn2 + LIF both axes -> packed spikes
    lif_dw_kernel<<<1536, 256, 0, stream>>>(
        A, wdw, bdw, sc1, sh1, sc2, sh2, tau1, vth1, tau2, vth2, S);

    // 4) both MFMA spike convs in ONE launch; gn4/gn5 stats fused
    conv_mfma_u8_kernel<<<4096, 256, 0, stream>>>(
        S, Wp2x, b21, b22, Tb3, Tb4, P4, P5);
    reduce_rows48_dual_kernel<<<384, 256, 0, stream>>>(
        P4, P5, 256, g4, be4, g5, be5, sc4, sh4, sc5, sh5);

    // 5) s_pre = leaky(gn4(t3)) + leaky(gn5(t4)) -> Tb3 in place; gn3 partials
    add_gn_nhwc_kernel<<<8192, 256, 0, stream>>>(Tb3, Tb4, sc4, sh4, sc5, sh5, Tb3, P6);
    reduce_rows48_dual_kernel<<<192, 256, 0, stream>>>(
        P6, P6, 1024, g3, be3, g3, be3, sc3, sh3, sc3, sh3);

    // 6) fold gn3 into per-batch W3, then final MFMA conv -> out (fp32 NCHW)
    pack_w3_kernel<<<98, 256, 0, stream>>>(w3, sc3, sh3, b3, Wp3, b3f);
    conv_mfma_f32out_kernel<<<2048, 256, 0, stream>>>(Tb3, Wp3, b3f, out);
}

// Round 10
// 239.235 us; speedup vs baseline: 1.2545x; 1.2545x over previous
//
#include <hip/hip_runtime.h>

#define NB 8
#define NC 48
#define NHW 65536
#define NTOT (NB*NC*NHW)

typedef __attribute__((ext_vector_type(8))) short short8;
typedef __attribute__((ext_vector_type(4))) float f32x4;

__device__ __forceinline__ float lrelu(float v) { return v >= 0.0f ? v : 0.1f * v; }

__device__ __forceinline__ unsigned short f2bf(float f) {
    unsigned int u = __float_as_uint(f);
    return (unsigned short)((u + 0x7fffu + ((u >> 16) & 1u)) >> 16);
}
__device__ __forceinline__ float bf2f(unsigned short v) {
    return __uint_as_float((unsigned int)v << 16);
}

// ---------------------------------------------------------------------------
// Merged weight prep: transpose w1 (vector conv) + pack w21/w22 (MFMA A-frag).
// ---------------------------------------------------------------------------
__global__ __launch_bounds__(256) void prep_kernel(
    const float* __restrict__ w1, const float* __restrict__ w21,
    const float* __restrict__ w22, float* __restrict__ Wt1,
    unsigned short* __restrict__ Wp)
{
    int i = blockIdx.x * 256 + threadIdx.x;
    if (i < 2304) {
        int o = i / 48, c = i % 48;
        Wt1[c * 48 + o] = w1[i];
    } else if (i < 2304 + 6144) {
        int e0 = i - 2304;
        int m = e0 / 3072, e = e0 % 3072;
        int mt = e >> 10, r2 = e & 1023, ks = r2 >> 9, r3 = r2 & 511;
        int lane = r3 >> 3, j = r3 & 7;
        int o = mt * 16 + (lane & 15), c = ks * 32 + (lane >> 4) * 8 + j;
        const float* W = m ? w22 : w21;
        float v = (c < 48) ? W[o * 48 + c] : 0.f;
        Wp[e0] = f2bf(v);
    }
}

// ---------------------------------------------------------------------------
// Pack per-batch gn3-folded w3: Wp3[b] = bf16(w3 * sc3[b]), and
// b3f[b][o] = b3[o] + sum_c w3[o][c]*sh3[b][c].
// ---------------------------------------------------------------------------
__global__ __launch_bounds__(256) void pack_w3_kernel(
    const float* __restrict__ w3, const float* __restrict__ sc3,
    const float* __restrict__ sh3, const float* __restrict__ b3,
    unsigned short* __restrict__ Wp3, float* __restrict__ b3f)
{
    int i = blockIdx.x * 256 + threadIdx.x;
    if (i < 24576) {
        int b = i / 3072, e = i % 3072;
        int mt = e >> 10, r2 = e & 1023, ks = r2 >> 9, r3 = r2 & 511;
        int lane = r3 >> 3, j = r3 & 7;
        int o = mt * 16 + (lane & 15), c = ks * 32 + (lane >> 4) * 8 + j;
        float v = (c < 48) ? w3[o * 48 + c] * sc3[b * 48 + c] : 0.f;
        Wp3[i] = f2bf(v);
    } else if (i < 24960) {
        int k = i - 24576;
        int b = k / 48, o = k % 48;
        float s = b3[o];
        for (int c = 0; c < 48; c++) s = fmaf(w3[o * 48 + c], sh3[b * 48 + c], s);
        b3f[k] = s;
    }
}

// ---------------------------------------------------------------------------
// conv1 (fp32, exact for the LIF path): round-5 structure (best measured).
// ---------------------------------------------------------------------------
__global__ __launch_bounds__(256) void conv48f_kernel(
    const float* __restrict__ in, const float* __restrict__ Wt,
    const float* __restrict__ bias, float* __restrict__ out,
    float* __restrict__ partial)
{
    int tid  = threadIdx.x;
    int lane = tid & 63;
    int wid  = tid >> 6;
    int blk  = blockIdx.x;
    int b    = blk >> 8;
    int px0  = (blk & 255) * 256 + lane * 4;
    int ob   = __builtin_amdgcn_readfirstlane(wid * 12);

    size_t base = (size_t)b * NC * NHW + px0;

    float acc[12][4];
#pragma unroll
    for (int o = 0; o < 12; o++) {
        float bz = bias[ob + o];
#pragma unroll
        for (int j = 0; j < 4; j++) acc[o][j] = bz;
    }

    float xv[2][4][4];
#pragma unroll
    for (int cc = 0; cc < 4; cc++) {
        float4 t = *(const float4*)(in + base + (size_t)cc * NHW);
        xv[0][cc][0] = t.x; xv[0][cc][1] = t.y;
        xv[0][cc][2] = t.z; xv[0][cc][3] = t.w;
    }

#pragma unroll
    for (int k = 0; k < 12; k++) {
        const int cur = k & 1;
        if (k < 11) {
            int cn = (k + 1) * 4;
#pragma unroll
            for (int cc = 0; cc < 4; cc++) {
                float4 t = *(const float4*)(in + base + (size_t)(cn + cc) * NHW);
                xv[cur ^ 1][cc][0] = t.x; xv[cur ^ 1][cc][1] = t.y;
                xv[cur ^ 1][cc][2] = t.z; xv[cur ^ 1][cc][3] = t.w;
            }
        }
        int c0 = k * 4;
#pragma unroll
        for (int cc = 0; cc < 4; cc++) {
            const float* wrow = Wt + (c0 + cc) * 48 + ob;
#pragma unroll
            for (int o = 0; o < 12; o++) {
                float wv = wrow[o];
#pragma unroll
                for (int j = 0; j < 4; j++)
                    acc[o][j] = fmaf(xv[cur][cc][j], wv, acc[o][j]);
            }
        }
        __builtin_amdgcn_sched_barrier(0);
    }

#pragma unroll
    for (int o = 0; o < 12; o++) {
        float4 t = {acc[o][0], acc[o][1], acc[o][2], acc[o][3]};
        *(float4*)(out + base + (size_t)(ob + o) * NHW) = t;
    }

#pragma unroll
    for (int i = 0; i < 6; i++) {
        float s = 0.f, q = 0.f;
#pragma unroll
        for (int k = 0; k < 2; k++)
#pragma unroll
            for (int j = 0; j < 4; j++) {
                float a = acc[2 * i + k][j];
                s += a;
                q = fmaf(a, a, q);
            }
#pragma unroll
        for (int off = 32; off; off >>= 1) {
            s += __shfl_down(s, off);
            q += __shfl_down(q, off);
        }
        if (lane == 0) {
            partial[(size_t)blk * 48 + ob + 2 * i]     = s;
            partial[(size_t)blk * 48 + ob + 2 * i + 1] = q;
        }
    }
}

// ---------------------------------------------------------------------------
// Depthwise 3x3 with gn1-apply + leaky fused; stores t2 + gn2 partials.
// (round-5 version — best measured dataflow)
// ---------------------------------------------------------------------------
__global__ __launch_bounds__(256) void dwconv_kernel(
    const float* __restrict__ in, const float* __restrict__ wdw,
    const float* __restrict__ bdw,
    const float* __restrict__ scale, const float* __restrict__ shift,
    float* __restrict__ out, float* __restrict__ partial)
{
    int tid = threadIdx.x;
    int blk = blockIdx.x;
    int bc  = blk >> 6;
    int rg  = blk & 63;
    int r   = tid >> 6;
    int w4  = tid & 63;
    int h   = rg * 4 + r;
    int c0  = w4 * 4;
    int c   = bc % 48;

    const float* plane = in + (size_t)bc * NHW;
    float sc = scale[bc], sh = shift[bc];

    float wk[9];
#pragma unroll
    for (int i = 0; i < 9; i++) wk[i] = wdw[c * 9 + i];
    float bv = bdw[c];

    float raw[3][6];
#pragma unroll
    for (int dy = 0; dy < 3; dy++) {
        int hh  = h + dy - 1;
        int hcl = min(max(hh, 0), 255);
        const float* row = plane + hcl * 256;
        float4 m  = *(const float4*)(row + c0);
        float lft = row[(w4 > 0) ? (c0 - 1) : 0];
        float rgt = row[(w4 < 63) ? (c0 + 4) : 255];
        raw[dy][0] = lft; raw[dy][1] = m.x; raw[dy][2] = m.y;
        raw[dy][3] = m.z; raw[dy][4] = m.w; raw[dy][5] = rgt;
    }

    float v[3][6];
#pragma unroll
    for (int dy = 0; dy < 3; dy++) {
        int hh = h + dy - 1;
        bool hv = (hh >= 0) && (hh < 256);
#pragma unroll
        for (int j = 0; j < 6; j++) {
            bool valid = hv && !(j == 0 && w4 == 0) && !(j == 5 && w4 == 63);
            float t = lrelu(fmaf(raw[dy][j], sc, sh));
            v[dy][j] = valid ? t : 0.f;
        }
    }

    float acc[4] = {bv, bv, bv, bv};
#pragma unroll
    for (int dy = 0; dy < 3; dy++)
#pragma unroll
        for (int dx = 0; dx < 3; dx++) {
            float wv = wk[dy * 3 + dx];
#pragma unroll
            for (int j = 0; j < 4; j++)
                acc[j] = fmaf(v[dy][j + dx], wv, acc[j]);
        }

    float4 o = {acc[0], acc[1], acc[2], acc[3]};
    *(float4*)(out + (size_t)bc * NHW + h * 256 + c0) = o;

    float s = (acc[0] + acc[1]) + (acc[2] + acc[3]);
    float q = fmaf(acc[0], acc[0], fmaf(acc[1], acc[1],
              fmaf(acc[2], acc[2], acc[3] * acc[3])));
#pragma unroll
    for (int off = 32; off; off >>= 1) {
        s += __shfl_down(s, off);
        q += __shfl_down(q, off);
    }
    __shared__ float red[8];
    int lane = tid & 63, wid = tid >> 6;
    if (lane == 0) { red[wid * 2] = s; red[wid * 2 + 1] = q; }
    __syncthreads();
    if (tid == 0) {
        partial[(size_t)blk * 2]     = red[0] + red[2] + red[4] + red[6];
        partial[(size_t)blk * 2 + 1] = red[1] + red[3] + red[5] + red[7];
    }
}

// ---------------------------------------------------------------------------
// Fused LIF over BOTH axes from ONE read of t2; packed spikes (bit0=H, bit1=W).
// ---------------------------------------------------------------------------
__global__ __launch_bounds__(256) void lif_fused_kernel(
    const float* __restrict__ in,
    const float* __restrict__ scale, const float* __restrict__ shift,
    const float* __restrict__ tau1p, const float* __restrict__ vth1p,
    const float* __restrict__ tau2p, const float* __restrict__ vth2p,
    unsigned char* __restrict__ spk)
{
    int id  = blockIdx.x * 256 + threadIdx.x;
    int ww4 = id & 15;
    int hh  = (id >> 4) & 63;
    int bc  = id >> 10;

    float sc = scale[bc], sh = shift[bc];
    float tau1 = tau1p[0], vth1 = vth1p[0];
    float tau2 = tau2p[0], vth2 = vth2p[0];

    const float* plane = in + (size_t)bc * NHW;

    float v[4][4][4];
#pragma unroll
    for (int t = 0; t < 4; t++)
#pragma unroll
        for (int u = 0; u < 4; u++) {
            float4 x = *(const float4*)(plane + (hh + 64 * t) * 256 + 64 * u + ww4 * 4);
            v[t][u][0] = lrelu(fmaf(x.x, sc, sh));
            v[t][u][1] = lrelu(fmaf(x.y, sc, sh));
            v[t][u][2] = lrelu(fmaf(x.z, sc, sh));
            v[t][u][3] = lrelu(fmaf(x.w, sc, sh));
        }

    unsigned int oC[4][4];
#pragma unroll
    for (int t = 0; t < 4; t++)
#pragma unroll
        for (int u = 0; u < 4; u++) oC[t][u] = 0u;

    {
        float mem[16];
#pragma unroll
        for (int k = 0; k < 16; k++) mem[k] = 0.f;
#pragma unroll
        for (int t = 0; t < 4; t++)
#pragma unroll
            for (int u = 0; u < 4; u++)
#pragma unroll
                for (int j = 0; j < 4; j++) {
                    float m = fmaf(mem[u * 4 + j], tau1, v[t][u][j]);
                    bool s = m > vth1;
                    oC[t][u] |= (s ? 1u : 0u) << (8 * j);
                    mem[u * 4 + j] = s ? 0.f : m;
                }
    }
    {
        float mem[16];
#pragma unroll
        for (int k = 0; k < 16; k++) mem[k] = 0.f;
#pragma unroll
        for (int u = 0; u < 4; u++)
#pragma unroll
            for (int t = 0; t < 4; t++)
#pragma unroll
                for (int j = 0; j < 4; j++) {
                    float m = fmaf(mem[t * 4 + j], tau2, v[t][u][j]);
                    bool s = m > vth2;
                    oC[t][u] |= (s ? 2u : 0u) << (8 * j);
                    mem[t * 4 + j] = s ? 0.f : m;
                }
    }

#pragma unroll
    for (int t = 0; t < 4; t++)
#pragma unroll
        for (int u = 0; u < 4; u++) {
            size_t off = (size_t)bc * NHW + (hh + 64 * t) * 256 + 64 * u + ww4 * 4;
            *(unsigned int*)(spk + off) = oC[t][u];
        }
}

// ---------------------------------------------------------------------------
// MFMA spike-conv STATS pass: reads packed spikes once (LDS), computes t3
// (bit0/w21) and t4 (bit1/w22) per-block channel stats sequentially.
// No tensor output — t3/t4 are recomputed bit-identically in the fused pass.
// ---------------------------------------------------------------------------
__global__ __launch_bounds__(256) void conv_mfma_stats_kernel(
    const unsigned char* __restrict__ spk,
    const unsigned short* __restrict__ Wp,
    const float* __restrict__ bias0, const float* __restrict__ bias1,
    float* __restrict__ P0, float* __restrict__ P1)
{
    __shared__ unsigned char Xs[64 * 264];
    __shared__ float red[4][96];

    int tid = threadIdx.x, lane = tid & 63, wid = tid >> 6;
    int l15 = lane & 15, g = lane >> 4;
    int blk = blockIdx.x;
    int b = blk >> 8, pix0 = (blk & 255) * 256;

    // stage packed u8, channel-major rows (stride 264); zero K-pad rows 48..63
    {
        int px = (tid & 63) * 4;
        int cw = tid >> 6;
#pragma unroll
        for (int r = 0; r < 12; r++) {
            int c = r * 4 + cw;
            uchar4 v = *(const uchar4*)(spk + ((size_t)(b * 48 + c) << 16) + pix0 + px);
            *(uchar4*)&Xs[c * 264 + px] = v;
        }
        unsigned int* Xw = (unsigned int*)&Xs[48 * 264];
        for (int i = tid; i < 1056; i += 256) Xw[i] = 0u;
    }
    __syncthreads();

#pragma unroll
    for (int m = 0; m < 2; m++) {
        const unsigned short* Wm = Wp + m * 3072;
        const float* bias = m ? bias1 : bias0;
        float* P = m ? P1 : P0;
        unsigned char msk = (unsigned char)(1u << m);

        short8 af[3][2];
#pragma unroll
        for (int mt = 0; mt < 3; mt++)
#pragma unroll
            for (int ks = 0; ks < 2; ks++)
                af[mt][ks] = *(const short8*)(Wm + (mt * 2 + ks) * 512 + lane * 8);

        f32x4 acc[3][4];
#pragma unroll
        for (int mt = 0; mt < 3; mt++) {
            f32x4 bv = *(const f32x4*)(bias + mt * 16 + g * 4);
#pragma unroll
            for (int nt = 0; nt < 4; nt++) acc[mt][nt] = bv;
        }

#pragma unroll
        for (int nt = 0; nt < 4; nt++) {
            int pixl = wid * 64 + nt * 16 + l15;
#pragma unroll
            for (int ks = 0; ks < 2; ks++) {
                int rb = ks * 32 + g * 8;
                short8 bf;
#pragma unroll
                for (int j = 0; j < 8; j++) {
                    unsigned char vv = Xs[(rb + j) * 264 + pixl];
                    bf[j] = (vv & msk) ? (short)0x3F80 : (short)0;
                }
#pragma unroll
                for (int mt = 0; mt < 3; mt++)
                    acc[mt][nt] = __builtin_amdgcn_mfma_f32_16x16x32_bf16(
                        af[mt][ks], bf, acc[mt][nt], 0, 0, 0);
            }
        }

#pragma unroll
        for (int mt = 0; mt < 3; mt++) {
#pragma unroll
            for (int r = 0; r < 4; r++) {
                float sl = 0.f, sq = 0.f;
#pragma unroll
                for (int nt = 0; nt < 4; nt++) {
                    float a = acc[mt][nt][r];
                    sl += a;
                    sq = fmaf(a, a, sq);
                }
#pragma unroll
                for (int off = 1; off < 16; off <<= 1) {
                    sl += __shfl_xor(sl, off);
                    sq += __shfl_xor(sq, off);
                }
                if (l15 == 0) {
                    int ch = mt * 16 + g * 4 + r;
                    red[wid][ch * 2]     = sl;
                    red[wid][ch * 2 + 1] = sq;
                }
            }
        }
        __syncthreads();
        if (tid < 96)
            P[(size_t)blk * 96 + tid] =
                red[0][tid] + red[1][tid] + red[2][tid] + red[3][tid];
        __syncthreads();
    }
}

// ---------------------------------------------------------------------------
// MFMA spike-conv FUSED pass: recomputes t3/t4 accs (bit-identical to stats
// pass), applies gn4/gn5 + leaky on the f32 accumulators, adds, writes
// s_pre (bf16 NHWC) + gn3 per-block channel stats. t3/t4 never hit memory.
// ---------------------------------------------------------------------------
__global__ __launch_bounds__(256) void conv_mfma_fused_kernel(
    const unsigned char* __restrict__ spk,
    const unsigned short* __restrict__ Wp,
    const float* __restrict__ bias0, const float* __restrict__ bias1,
    const float* __restrict__ sc4, const float* __restrict__ sh4,
    const float* __restrict__ sc5, const float* __restrict__ sh5,
    unsigned short* __restrict__ outp, float* __restrict__ P)
{
    __shared__ unsigned char Xs[64 * 264];
    __shared__ float red[4][96];

    int tid = threadIdx.x, lane = tid & 63, wid = tid >> 6;
    int l15 = lane & 15, g = lane >> 4;
    int blk = blockIdx.x;
    int b = blk >> 8, pix0 = (blk & 255) * 256;

    {
        int px = (tid & 63) * 4;
        int cw = tid >> 6;
#pragma unroll
        for (int r = 0; r < 12; r++) {
            int c = r * 4 + cw;
            uchar4 v = *(const uchar4*)(spk + ((size_t)(b * 48 + c) << 16) + pix0 + px);
            *(uchar4*)&Xs[c * 264 + px] = v;
        }
        unsigned int* Xw = (unsigned int*)&Xs[48 * 264];
        for (int i = tid; i < 1056; i += 256) Xw[i] = 0u;
    }
    __syncthreads();

    f32x4 acc0[3][4];   // gn4+leaky(t3)
    // ---- pass 0: bit0 (H spikes) with w21 ----
    {
        short8 af[3][2];
#pragma unroll
        for (int mt = 0; mt < 3; mt++)
#pragma unroll
            for (int ks = 0; ks < 2; ks++)
                af[mt][ks] = *(const short8*)(Wp + (mt * 2 + ks) * 512 + lane * 8);

#pragma unroll
        for (int mt = 0; mt < 3; mt++) {
            f32x4 bv = *(const f32x4*)(bias0 + mt * 16 + g * 4);
#pragma unroll
            for (int nt = 0; nt < 4; nt++) acc0[mt][nt] = bv;
        }

#pragma unroll
        for (int nt = 0; nt < 4; nt++) {
            int pixl = wid * 64 + nt * 16 + l15;
#pragma unroll
            for (int ks = 0; ks < 2; ks++) {
                int rb = ks * 32 + g * 8;
                short8 bf;
#pragma unroll
                for (int j = 0; j < 8; j++) {
                    unsigned char vv = Xs[(rb + j) * 264 + pixl];
                    bf[j] = (vv & 1) ? (short)0x3F80 : (short)0;
                }
#pragma unroll
                for (int mt = 0; mt < 3; mt++)
                    acc0[mt][nt] = __builtin_amdgcn_mfma_f32_16x16x32_bf16(
                        af[mt][ks], bf, acc0[mt][nt], 0, 0, 0);
            }
        }

        // gn4 + leaky in place (f32)
#pragma unroll
        for (int mt = 0; mt < 3; mt++) {
            f32x4 scv = *(const f32x4*)(sc4 + b * 48 + mt * 16 + g * 4);
            f32x4 shv = *(const f32x4*)(sh4 + b * 48 + mt * 16 + g * 4);
#pragma unroll
            for (int nt = 0; nt < 4; nt++)
#pragma unroll
                for (int r = 0; r < 4; r++)
                    acc0[mt][nt][r] = lrelu(fmaf(acc0[mt][nt][r], scv[r], shv[r]));
        }
    }

    // ---- pass 1: bit1 (W spikes) with w22; combine + store + gn3 stats ----
    {
        short8 af[3][2];
#pragma unroll
        for (int mt = 0; mt < 3; mt++)
#pragma unroll
            for (int ks = 0; ks < 2; ks++)
                af[mt][ks] = *(const short8*)(Wp + 3072 + (mt * 2 + ks) * 512 + lane * 8);

        f32x4 acc1[3][4];
#pragma unroll
        for (int mt = 0; mt < 3; mt++) {
            f32x4 bv = *(const f32x4*)(bias1 + mt * 16 + g * 4);
#pragma unroll
            for (int nt = 0; nt < 4; nt++) acc1[mt][nt] = bv;
        }

#pragma unroll
        for (int nt = 0; nt < 4; nt++) {
            int pixl = wid * 64 + nt * 16 + l15;
#pragma unroll
            for (int ks = 0; ks < 2; ks++) {
                int rb = ks * 32 + g * 8;
                short8 bf;
#pragma unroll
                for (int j = 0; j < 8; j++) {
                    unsigned char vv = Xs[(rb + j) * 264 + pixl];
                    bf[j] = (vv & 2) ? (short)0x3F80 : (short)0;
                }
#pragma unroll
                for (int mt = 0; mt < 3; mt++)
                    acc1[mt][nt] = __builtin_amdgcn_mfma_f32_16x16x32_bf16(
                        af[mt][ks], bf, acc1[mt][nt], 0, 0, 0);
            }
        }

        // s = acc0 + lrelu(gn5(acc1)); store NHWC bf16; gn3 stats
#pragma unroll
        for (int mt = 0; mt < 3; mt++) {
            f32x4 scv = *(const f32x4*)(sc5 + b * 48 + mt * 16 + g * 4);
            f32x4 shv = *(const f32x4*)(sh5 + b * 48 + mt * 16 + g * 4);
#pragma unroll
            for (int nt = 0; nt < 4; nt++)
#pragma unroll
                for (int r = 0; r < 4; r++)
                    acc1[mt][nt][r] = acc0[mt][nt][r] +
                        lrelu(fmaf(acc1[mt][nt][r], scv[r], shv[r]));
        }

#pragma unroll
        for (int nt = 0; nt < 4; nt++) {
            int px = pix0 + wid * 64 + nt * 16 + l15;
            size_t obase = ((size_t)b * NHW + px) * 48;
#pragma unroll
            for (int mt = 0; mt < 3; mt++) {
                ushort4 o;
                o.x = f2bf(acc1[mt][nt][0]); o.y = f2bf(acc1[mt][nt][1]);
                o.z = f2bf(acc1[mt][nt][2]); o.w = f2bf(acc1[mt][nt][3]);
                *(ushort4*)(outp + obase + mt * 16 + g * 4) = o;
            }
        }

#pragma unroll
        for (int mt = 0; mt < 3; mt++) {
#pragma unroll
            for (int r = 0; r < 4; r++) {
                float sl = 0.f, sq = 0.f;
#pragma unroll
                for (int nt = 0; nt < 4; nt++) {
                    float a = acc1[mt][nt][r];
                    sl += a;
                    sq = fmaf(a, a, sq);
                }
#pragma unroll
                for (int off = 1; off < 16; off <<= 1) {
                    sl += __shfl_xor(sl, off);
                    sq += __shfl_xor(sq, off);
                }
                if (l15 == 0) {
                    int ch = mt * 16 + g * 4 + r;
                    red[wid][ch * 2]     = sl;
                    red[wid][ch * 2 + 1] = sq;
                }
            }
        }
        __syncthreads();
        if (tid < 96)
            P[(size_t)blk * 96 + tid] =
                red[0][tid] + red[1][tid] + red[2][tid] + red[3][tid];
    }
}

// ---------------------------------------------------------------------------
// MFMA 1x1 conv: bf16 NHWC s_pre -> fp32 NCHW out. gn3 folded into per-batch
// weights. All 8 B-fragments prefetched before the MFMA chain.
// ---------------------------------------------------------------------------
__global__ __launch_bounds__(256) void conv_mfma_f32out_kernel(
    const unsigned short* __restrict__ sp, const unsigned short* __restrict__ Wp3,
    const float* __restrict__ b3f, float* __restrict__ outp)
{
    int tid = threadIdx.x, lane = tid & 63, wid = tid >> 6;
    int l15 = lane & 15, g = lane >> 4;
    int blk = blockIdx.x, b = blk >> 8, pix0 = (blk & 255) * 256;

    const unsigned short* Wb = Wp3 + b * 3072;

    short8 bfr[4][2];
#pragma unroll
    for (int nt = 0; nt < 4; nt++) {
        size_t pb = ((size_t)b * NHW + pix0 + wid * 64 + nt * 16 + l15) * 48;
#pragma unroll
        for (int ks = 0; ks < 2; ks++)
            bfr[nt][ks] = *(const short8*)(sp + pb + ks * 32 + g * 8);
    }

    short8 af[3][2];
#pragma unroll
    for (int mt = 0; mt < 3; mt++)
#pragma unroll
        for (int ks = 0; ks < 2; ks++)
            af[mt][ks] = *(const short8*)(Wb + (mt * 2 + ks) * 512 + lane * 8);

    f32x4 acc[3][4];
#pragma unroll
    for (int mt = 0; mt < 3; mt++) {
        f32x4 bv = *(const f32x4*)(b3f + b * 48 + mt * 16 + g * 4);
#pragma unroll
        for (int nt = 0; nt < 4; nt++) acc[mt][nt] = bv;
    }

#pragma unroll
    for (int nt = 0; nt < 4; nt++)
#pragma unroll
        for (int ks = 0; ks < 2; ks++)
#pragma unroll
            for (int mt = 0; mt < 3; mt++)
                acc[mt][nt] = __builtin_amdgcn_mfma_f32_16x16x32_bf16(
                    af[mt][ks], bfr[nt][ks], acc[mt][nt], 0, 0, 0);

#pragma unroll
    for (int nt = 0; nt < 4; nt++) {
        int px = pix0 + wid * 64 + nt * 16 + l15;
#pragma unroll
        for (int mt = 0; mt < 3; mt++)
#pragma unroll
            for (int r = 0; r < 4; r++)
                outp[((size_t)(b * 48 + mt * 16 + g * 4 + r) << 16) + px] = acc[mt][nt][r];
    }
}

// ---------------------------------------------------------------------------
// Reduce P1 layout (conv1): P[(b*256+chunk)*48 + 2g {,+1}]
// ---------------------------------------------------------------------------
__global__ __launch_bounds__(256) void reduce_chunked48_kernel(
    const float* __restrict__ P, const float* __restrict__ gamma,
    const float* __restrict__ beta,
    float* __restrict__ scale, float* __restrict__ shift)
{
    int b = blockIdx.x / 24, g = blockIdx.x % 24;
    int tid = threadIdx.x;
    double s = (double)P[(size_t)(b * 256 + tid) * 48 + 2 * g];
    double q = (double)P[(size_t)(b * 256 + tid) * 48 + 2 * g + 1];
    __shared__ double ls[256], lq[256];
    ls[tid] = s; lq[tid] = q;
    __syncthreads();
    for (int st = 128; st; st >>= 1) {
        if (tid < st) { ls[tid] += ls[tid + st]; lq[tid] += lq[tid + st]; }
        __syncthreads();
    }
    if (tid == 0) {
        double mu  = ls[0] / 131072.0;
        double var = lq[0] / 131072.0 - mu * mu;
        double rstd = 1.0 / sqrt(var + 1e-5);
#pragma unroll
        for (int j = 0; j < 2; j++) {
            int c = 2 * g + j;
            double scv = rstd * (double)gamma[c];
            scale[b * 48 + c] = (float)scv;
            shift[b * 48 + c] = (float)((double)beta[c] - mu * scv);
        }
    }
}

// ---------------------------------------------------------------------------
// Reduce per-plane partials (dwconv): P[((b*48+c)*chunks + k)*2 {,+1}]
// ---------------------------------------------------------------------------
__global__ __launch_bounds__(256) void reduce_plane_kernel(
    const float* __restrict__ P, int chunks,
    const float* __restrict__ gamma, const float* __restrict__ beta,
    float* __restrict__ scale, float* __restrict__ shift)
{
    int b = blockIdx.x / 24, g = blockIdx.x % 24;
    int tid = threadIdx.x;
    double s = 0.0, q = 0.0;
    for (int i = tid; i < 2 * chunks; i += 256) {
        int j = (i >= chunks) ? 1 : 0;
        int k = i - j * chunks;
        const float* p = P + ((size_t)((b * 48 + 2 * g + j) * chunks + k)) * 2;
        s += (double)p[0];
        q += (double)p[1];
    }
    __shared__ double ls[256], lq[256];
    ls[tid] = s; lq[tid] = q;
    __syncthreads();
    for (int st = 128; st; st >>= 1) {
        if (tid < st) { ls[tid] += ls[tid + st]; lq[tid] += lq[tid + st]; }
        __syncthreads();
    }
    if (tid == 0) {
        double mu  = ls[0] / 131072.0;
        double var = lq[0] / 131072.0 - mu * mu;
        double rstd = 1.0 / sqrt(var + 1e-5);
#pragma unroll
        for (int j = 0; j < 2; j++) {
            int c = 2 * g + j;
            double scv = rstd * (double)gamma[c];
            scale[b * 48 + c] = (float)scv;
            shift[b * 48 + c] = (float)((double)beta[c] - mu * scv);
        }
    }
}

// ---------------------------------------------------------------------------
// Reduce row-partials P[row*96 + c*2 {,+1}]; one or two sets per launch.
// ---------------------------------------------------------------------------
__global__ __launch_bounds__(256) void reduce_rows48_dual_kernel(
    const float* __restrict__ PA, const float* __restrict__ PB, int rows_per_b,
    const float* __restrict__ gA, const float* __restrict__ beA,
    const float* __restrict__ gB, const float* __restrict__ beB,
    float* __restrict__ scA, float* __restrict__ shA,
    float* __restrict__ scB, float* __restrict__ shB)
{
    int sel = blockIdx.x / 192;
    int idx = blockIdx.x % 192;
    const float* P     = sel ? PB : PA;
    const float* gamma = sel ? gB : gA;
    const float* beta  = sel ? beB : beA;
    float* scale = sel ? scB : scA;
    float* shift = sel ? shB : shA;

    int b = idx / 24, g = idx % 24;
    int tid = threadIdx.x;
    double s = 0.0, q = 0.0;
    for (int r = tid; r < rows_per_b; r += 256) {
        const float* p = P + (size_t)(b * rows_per_b + r) * 96;
        s += (double)p[4 * g] + (double)p[4 * g + 2];
        q += (double)p[4 * g + 1] + (double)p[4 * g + 3];
    }
    __shared__ double ls[256], lq[256];
    ls[tid] = s; lq[tid] = q;
    __syncthreads();
    for (int st = 128; st; st >>= 1) {
        if (tid < st) { ls[tid] += ls[tid + st]; lq[tid] += lq[tid + st]; }
        __syncthreads();
    }
    if (tid == 0) {
        double mu  = ls[0] / 131072.0;
        double var = lq[0] / 131072.0 - mu * mu;
        double rstd = 1.0 / sqrt(var + 1e-5);
#pragma unroll
        for (int j = 0; j < 2; j++) {
            int c = 2 * g + j;
            double scv = rstd * (double)gamma[c];
            scale[b * 48 + c] = (float)scv;
            shift[b * 48 + c] = (float)((double)beta[c] - mu * scv);
        }
    }
}

// ---------------------------------------------------------------------------
extern "C" void kernel_launch(void* const* d_in, const int* in_sizes, int n_in,
                              void* d_out, int out_size, void* d_ws, size_t ws_size,
                              hipStream_t stream)
{
    const float* x    = (const float*)d_in[0];
    const float* w1   = (const float*)d_in[1];
    const float* b1   = (const float*)d_in[2];
    const float* wdw  = (const float*)d_in[3];
    const float* bdw  = (const float*)d_in[4];
    const float* w21  = (const float*)d_in[5];
    const float* b21  = (const float*)d_in[6];
    const float* w22  = (const float*)d_in[7];
    const float* b22  = (const float*)d_in[8];
    const float* w3   = (const float*)d_in[9];
    const float* b3   = (const float*)d_in[10];
    const float* g1   = (const float*)d_in[11];
    const float* be1  = (const float*)d_in[12];
    const float* g2   = (const float*)d_in[13];
    const float* be2  = (const float*)d_in[14];
    const float* g3   = (const float*)d_in[15];
    const float* be3  = (const float*)d_in[16];
    const float* g4   = (const float*)d_in[17];
    const float* be4  = (const float*)d_in[18];
    const float* g5   = (const float*)d_in[19];
    const float* be5  = (const float*)d_in[20];
    const float* tau1 = (const float*)d_in[21];
    const float* vth1 = (const float*)d_in[22];
    const float* tau2 = (const float*)d_in[23];
    const float* vth2 = (const float*)d_in[24];

    float* out = (float*)d_out;
    char*  ws  = (char*)d_ws;

    // ws layout: A (t1 fp32) aliases Tb3 (s_pre bf16) — A dead before s_pre.
    float*          A   = (float*)ws;                                // t1 fp32 (NTOT)
    unsigned short* Tb3 = (unsigned short*)ws;                       // s_pre bf16 NHWC
    unsigned char*  S   = (unsigned char*)(ws + (size_t)NTOT * 4);   // packed spikes
    char* p = ws + (size_t)NTOT * 5;
    float* P1 = (float*)p;  p += (size_t)2048 * 48 * 4;
    float* P2 = (float*)p;  p += (size_t)24576 * 2 * 4;
    float* P4 = (float*)p;  p += (size_t)2048 * 96 * 4;
    float* P5 = (float*)p;  p += (size_t)2048 * 96 * 4;
    float* P6 = (float*)p;  p += (size_t)2048 * 96 * 4;
    float* sc1 = (float*)p; p += 384 * 4;  float* sh1 = (float*)p; p += 384 * 4;
    float* sc2 = (float*)p; p += 384 * 4;  float* sh2 = (float*)p; p += 384 * 4;
    float* sc3 = (float*)p; p += 384 * 4;  float* sh3 = (float*)p; p += 384 * 4;
    float* sc4 = (float*)p; p += 384 * 4;  float* sh4 = (float*)p; p += 384 * 4;
    float* sc5 = (float*)p; p += 384 * 4;  float* sh5 = (float*)p; p += 384 * 4;
    float*          Wt1  = (float*)p;          p += 2304 * 4;
    unsigned short* Wp2x = (unsigned short*)p; p += 6144 * 2;
    unsigned short* Wp3  = (unsigned short*)p; p += 24576 * 2;
    float*          b3f  = (float*)p;          p += 384 * 4;

    // 0) weight prep (merged)
    prep_kernel<<<33, 256, 0, stream>>>(w1, w21, w22, Wt1, Wp2x);

    // 1) t1 = conv1x1(x, w1) + b1 -> A (fp32 NCHW); gn1 partials
    conv48f_kernel<<<2048, 256, 0, stream>>>(x, Wt1, b1, A, P1);
    reduce_chunked48_kernel<<<192, 256, 0, stream>>>(P1, g1, be1, sc1, sh1);

    // 2) t2 = dwconv3x3(leaky(gn1(A))) -> out (scratch); gn2 partials
    dwconv_kernel<<<24576, 256, 0, stream>>>(A, wdw, bdw, sc1, sh1, out, P2);
    reduce_plane_kernel<<<192, 256, 0, stream>>>(P2, 64, g2, be2, sc2, sh2);

    // 3) both LIF spike trains -> packed u8 (bit0=H, bit1=W)
    lif_fused_kernel<<<1536, 256, 0, stream>>>(out, sc2, sh2, tau1, vth1, tau2, vth2, S);

    // 4) t3/t4 stats only (no tensor store); gn4/gn5 reduce
    conv_mfma_stats_kernel<<<2048, 256, 0, stream>>>(S, Wp2x, b21, b22, P4, P5);
    reduce_rows48_dual_kernel<<<384, 256, 0, stream>>>(
        P4, P5, 256, g4, be4, g5, be5, sc4, sh4, sc5, sh5);

    // 5) recompute t3/t4 + gn4/gn5+leaky+add fused -> s_pre (Tb3); gn3 partials
    conv_mfma_fused_kernel<<<2048, 256, 0, stream>>>(
        S, Wp2x, b21, b22, sc4, sh4, sc5, sh5, Tb3, P6);
    reduce_rows48_dual_kernel<<<192, 256, 0, stream>>>(
        P6, P6, 256, g3, be3, g3, be3, sc3, sh3, sc3, sh3);

    // 6) fold gn3 into per-batch W3, then final MFMA conv -> out (fp32 NCHW)
    pack_w3_kernel<<<98, 256, 0, stream>>>(w3, sc3, sh3, b3, Wp3, b3f);
    conv_mfma_f32out_kernel<<<2048, 256, 0, stream>>>(Tb3, Wp3, b3f, out);
}